// Round 2
// baseline (1153.617 us; speedup 1.0000x reference)
//
#include <hip/hip_runtime.h>
#include <cstdint>

// Problem constants
// B=4 per input, H=W=64, N=4096 pixels, C3=256 final channels.
// Inputs (setup_inputs order): x1, x2, w1, b1, w2, b2, w3, b3  (all fp32)
// Output: (4, 512, 64, 64) fp32; channels 0..255 = f1, 256..511 = gathered f2.

#define NPX 4096

// ---------------------------------------------------------------------------
// conv1: 1 -> 32 channels, trivial direct conv. One thread per output element.
// ---------------------------------------------------------------------------
__global__ __launch_bounds__(256) void conv1_k(
    const float* __restrict__ x1, const float* __restrict__ x2,
    const float* __restrict__ w,  const float* __restrict__ bias,
    float* __restrict__ y1)
{
    int gid = blockIdx.x * 256 + threadIdx.x;        // 8*32*4096 = 1,048,576
    int px  = gid & 4095;
    int co  = (gid >> 12) & 31;
    int img = gid >> 17;
    const float* xin = (img < 4) ? (x1 + (size_t)img * NPX)
                                 : (x2 + (size_t)(img - 4) * NPX);
    int r = px >> 6, c = px & 63;
    float acc = bias[co];
#pragma unroll
    for (int dy = 0; dy < 3; ++dy) {
        int rr = r + dy - 1;
        if (rr < 0 || rr > 63) continue;
#pragma unroll
        for (int dx = 0; dx < 3; ++dx) {
            int cc = c + dx - 1;
            if (cc < 0 || cc > 63) continue;
            acc = fmaf(w[co * 9 + dy * 3 + dx], xin[rr * 64 + cc], acc);
        }
    }
    y1[(size_t)img * 32 * NPX + (size_t)co * NPX + px] = acc;
}

// ---------------------------------------------------------------------------
// conv23: generic 3x3 SAME conv, CI input channels, 64 output channels per
// block (blockIdx.z selects the 64-channel group). Block = (img, row, cogrp),
// 256 threads: co = tid&63, seg = tid>>6 (4 segments x 16 px of the row).
// Input row slab (3 rows x 64 cols x CI) staged in LDS once; weights staged
// in LDS in ci-chunks of 8 with padded stride to spread banks.
// ---------------------------------------------------------------------------
template <int CI>
__global__ __launch_bounds__(256) void conv23_k(
    const float* __restrict__ in,     // [8][CI][64][64]
    const float* __restrict__ w,      // [CO_total][CI][3][3]
    const float* __restrict__ bias,   // [CO_total]
    float* __restrict__ outA,         // dest for img 0..3
    float* __restrict__ outB,         // dest for img 4..7
    int strideA, int strideB)         // per-img float strides of dests
{
    constexpr int CIC  = 8;           // ci chunk
    constexpr int PADW = CIC * 9 + 1; // 73, odd -> bank spread
    __shared__ float in_lds[CI * 3 * 64];
    __shared__ float w_lds[64 * PADW];

    const int row  = blockIdx.x;
    const int img  = blockIdx.y;
    const int cob  = blockIdx.z * 64;     // channel-group base
    const int tid  = threadIdx.x;
    const int cow  = tid & 63;            // local out channel
    const int seg  = tid >> 6;            // 0..3
    const int c0   = seg * 16;

    // stage input slab: rows row-1..row+1, zero-filled at image border
    const float* ib = in + (size_t)img * CI * NPX;
    for (int idx = tid; idx < CI * 3 * 64; idx += 256) {
        int ci  = idx / 192;
        int rem = idx - ci * 192;
        int dy  = rem >> 6;
        int col = rem & 63;
        int gr  = row + dy - 1;
        float v = 0.f;
        if (gr >= 0 && gr < 64) v = ib[(size_t)ci * NPX + gr * 64 + col];
        in_lds[idx] = v;
    }

    float acc[16];
    {
        float bv = bias[cob + cow];
#pragma unroll
        for (int p = 0; p < 16; ++p) acc[p] = bv;
    }

    for (int cic = 0; cic < CI; cic += CIC) {
        __syncthreads();   // prev compute done (and in_lds visible on iter 0)
        // stage weights for this ci chunk: [64 co][CIC*9]
        for (int k = tid; k < 64 * CIC * 9; k += 256) {
            int co_l = k / (CIC * 9);
            int r    = k - co_l * (CIC * 9);
            w_lds[co_l * PADW + r] =
                w[(size_t)(cob + co_l) * CI * 9 + (size_t)cic * 9 + r];
        }
        __syncthreads();

#pragma unroll
        for (int ci_l = 0; ci_l < CIC; ++ci_l) {
            float wv[9];
#pragma unroll
            for (int t = 0; t < 9; ++t)
                wv[t] = w_lds[cow * PADW + ci_l * 9 + t];
#pragma unroll
            for (int dy = 0; dy < 3; ++dy) {
                const float* rp = &in_lds[((cic + ci_l) * 3 + dy) * 64 + c0];
                float v[18];
                v[0]  = (c0 == 0)  ? 0.f : rp[-1];
#pragma unroll
                for (int p = 0; p < 16; ++p) v[p + 1] = rp[p];
                v[17] = (c0 == 48) ? 0.f : rp[16];
#pragma unroll
                for (int p = 0; p < 16; ++p) {
                    acc[p] = fmaf(wv[dy * 3 + 0], v[p],     acc[p]);
                    acc[p] = fmaf(wv[dy * 3 + 1], v[p + 1], acc[p]);
                    acc[p] = fmaf(wv[dy * 3 + 2], v[p + 2], acc[p]);
                }
            }
        }
    }

    float* dst = (img < 4) ? (outA + (size_t)img * strideA)
                           : (outB + (size_t)(img - 4) * strideB);
    dst += (size_t)(cob + cow) * NPX + row * 64 + c0;
#pragma unroll
    for (int p = 0; p < 16; ++p) dst[p] = acc[p];
}

// ---------------------------------------------------------------------------
// normB: ||f2_j||^2 per (b, j); also inits minkey to all-ones.
// ---------------------------------------------------------------------------
__global__ __launch_bounds__(256) void normb_k(
    const float* __restrict__ f2, float* __restrict__ normB,
    unsigned long long* __restrict__ minkey)
{
    int gid = blockIdx.x * 256 + threadIdx.x;   // 4*4096
    int b = gid >> 12, j = gid & 4095;
    const float* p = f2 + (size_t)b * 256 * NPX + j;
    float s = 0.f;
#pragma unroll 8
    for (int c = 0; c < 256; ++c) {
        float v = p[(size_t)c * NPX];
        s = fmaf(v, v, s);
    }
    normB[gid] = s;
    minkey[gid] = ~0ull;
}

// ---------------------------------------------------------------------------
// gemm_argmin: per batch, cross = f1^T f2 tile (128i x 128j), fused
// key = ||f2_j||^2 - 2*cross; block-local min then global atomicMin on
// packed (orderable-float << 32 | j) so tie-break = smallest j (JAX argmin).
// Block 256 = 16(ti) x 16(tj); each thread owns an 8x8 register tile.
// ---------------------------------------------------------------------------
__global__ __launch_bounds__(256) void gemm_argmin_k(
    const float* __restrict__ f1base,   // d_out, per-b stride 512*NPX, ch 0..255
    const float* __restrict__ f2base,   // ws,   per-b stride 256*NPX
    const float* __restrict__ normB,    // [4][4096]
    unsigned long long* __restrict__ minkey)  // [4][4096]
{
    __shared__ float smem[8192];        // As[32][128] | Bs[32][128] = 32 KB
    float* As = smem;                   // As[c][i_local]
    float* Bs = smem + 4096;            // Bs[c][j_local]

    const int b  = blockIdx.z;
    const int i0 = blockIdx.y * 128;
    const int j0 = blockIdx.x * 128;
    const float* f1 = f1base + (size_t)b * 512 * NPX;
    const float* f2 = f2base + (size_t)b * 256 * NPX;
    const int tid = threadIdx.x;
    const int ti = tid & 15, tj = tid >> 4;

    float acc[8][8];
#pragma unroll
    for (int i = 0; i < 8; ++i)
#pragma unroll
        for (int j = 0; j < 8; ++j) acc[i][j] = 0.f;

    for (int cb = 0; cb < 256; cb += 32) {
#pragma unroll
        for (int k = 0; k < 4; ++k) {            // A: 32x128 = 1024 float4
            int kk = tid + k * 256;
            int r = kk >> 5, col = kk & 31;
            *(float4*)&As[r * 128 + col * 4] =
                *(const float4*)&f1[(size_t)(cb + r) * NPX + i0 + col * 4];
        }
#pragma unroll
        for (int k = 0; k < 4; ++k) {            // B: 32x128 = 1024 float4
            int kk = tid + k * 256;
            int r = kk >> 5, col = kk & 31;
            *(float4*)&Bs[r * 128 + col * 4] =
                *(const float4*)&f2[(size_t)(cb + r) * NPX + j0 + col * 4];
        }
        __syncthreads();

#pragma unroll 8
        for (int c = 0; c < 32; ++c) {
            float4 a0 = *(float4*)&As[c * 128 + ti * 8];
            float4 a1 = *(float4*)&As[c * 128 + ti * 8 + 4];
            float4 b0 = *(float4*)&Bs[c * 128 + tj * 8];
            float4 b1 = *(float4*)&Bs[c * 128 + tj * 8 + 4];
            float av[8] = {a0.x, a0.y, a0.z, a0.w, a1.x, a1.y, a1.z, a1.w};
            float bv[8] = {b0.x, b0.y, b0.z, b0.w, b1.x, b1.y, b1.z, b1.w};
#pragma unroll
            for (int i = 0; i < 8; ++i)
#pragma unroll
                for (int j = 0; j < 8; ++j)
                    acc[i][j] = fmaf(av[i], bv[j], acc[i][j]);
        }
        __syncthreads();
    }

    // epilogue: dist-key = normB[j] - 2*cross, packed with j; reduce over tj.
    // Reuse smem as u64 red[128][17] (17.4 KB <= 32 KB), stride 17 kills the
    // 16-way bank conflict of a power-of-2 stride.
    float nb[8];
#pragma unroll
    for (int j = 0; j < 8; ++j) nb[j] = normB[b * 4096 + j0 + tj * 8 + j];

    unsigned long long* red = (unsigned long long*)smem;
#pragma unroll
    for (int ii = 0; ii < 8; ++ii) {
        unsigned long long kb = ~0ull;
#pragma unroll
        for (int j = 0; j < 8; ++j) {
            float d = fmaf(-2.f, acc[ii][j], nb[j]);
            unsigned u = __float_as_uint(d);
            u = (u & 0x80000000u) ? ~u : (u | 0x80000000u);
            unsigned long long key =
                ((unsigned long long)u << 32) | (unsigned)(j0 + tj * 8 + j);
            kb = kb < key ? kb : key;
        }
        red[(ti * 8 + ii) * 17 + tj] = kb;
    }
    __syncthreads();
    if (tid < 128) {
        unsigned long long m = red[tid * 17];
#pragma unroll
        for (int t = 1; t < 16; ++t) {
            unsigned long long v = red[tid * 17 + t];
            m = m < v ? m : v;
        }
        atomicMin(&minkey[(size_t)b * 4096 + i0 + tid], m);
    }
}

// ---------------------------------------------------------------------------
// gather: out[b][256+c][px] = f2[b][c][idx(b,px)]
// ---------------------------------------------------------------------------
__global__ __launch_bounds__(256) void gather_k(
    const unsigned long long* __restrict__ minkey,
    const float* __restrict__ f2, float* __restrict__ out)
{
    int b  = blockIdx.y;
    int px = blockIdx.x * 256 + threadIdx.x;
    int idx = (int)(unsigned)(minkey[(size_t)b * 4096 + px] & 0xffffffffu);
    const float* src = f2 + (size_t)b * 256 * NPX;
    float* dst = out + (size_t)b * 512 * NPX + (size_t)256 * NPX + px;
#pragma unroll 4
    for (int c = 0; c < 256; ++c)
        dst[(size_t)c * NPX] = src[(size_t)c * NPX + idx];
}

// ---------------------------------------------------------------------------
extern "C" void kernel_launch(void* const* d_in, const int* in_sizes, int n_in,
                              void* d_out, int out_size, void* d_ws, size_t ws_size,
                              hipStream_t stream)
{
    const float* x1 = (const float*)d_in[0];
    const float* x2 = (const float*)d_in[1];
    const float* w1 = (const float*)d_in[2];
    const float* b1 = (const float*)d_in[3];
    const float* w2 = (const float*)d_in[4];
    const float* b2 = (const float*)d_in[5];
    const float* w3 = (const float*)d_in[6];
    const float* b3 = (const float*)d_in[7];
    float* out = (float*)d_out;
    char* ws = (char*)d_ws;

    // workspace layout (bytes)
    float* y1 = (float*)(ws);                          //  8*32*4096*4 = 4 MB
    float* y2 = (float*)(ws + 4194304);                //  8*64*4096*4 = 8 MB
    float* f2 = (float*)(ws + 12582912);               //  4*256*4096*4 = 16 MB
    float* normB = (float*)(ws + 29360128);            //  64 KB
    unsigned long long* minkey =
        (unsigned long long*)(ws + 29425664);          // 128 KB

    conv1_k<<<4096, 256, 0, stream>>>(x1, x2, w1, b1, y1);

    conv23_k<32><<<dim3(64, 8, 1), 256, 0, stream>>>(
        y1, w2, b2, y2, y2 + (size_t)4 * 64 * NPX, 64 * NPX, 64 * NPX);

    // conv3: img 0..3 -> d_out channels 0..255 (that IS f1); img 4..7 -> ws f2
    conv23_k<64><<<dim3(64, 8, 4), 256, 0, stream>>>(
        y2, w3, b3, out, f2, 512 * NPX, 256 * NPX);

    normb_k<<<64, 256, 0, stream>>>(f2, normB, minkey);

    gemm_argmin_k<<<dim3(32, 32, 4), 256, 0, stream>>>(out, f2, normB, minkey);

    gather_k<<<dim3(16, 4), 256, 0, stream>>>(minkey, f2, out);
}

// Round 3
// 708.186 us; speedup vs baseline: 1.6290x; 1.6290x over previous
//
#include <hip/hip_runtime.h>
#include <cstdint>

// Problem constants
// B=4 per input, H=W=64, N=4096 pixels, C3=256 final channels.
// Inputs (setup_inputs order): x1, x2, w1, b1, w2, b2, w3, b3  (all fp32)
// Output: (4, 512, 64, 64) fp32; channels 0..255 = f1, 256..511 = gathered f2.

#define NPX 4096

// ---------------------------------------------------------------------------
// conv1: 1 -> 32 channels, trivial direct conv. One thread per output element.
// ---------------------------------------------------------------------------
__global__ __launch_bounds__(256) void conv1_k(
    const float* __restrict__ x1, const float* __restrict__ x2,
    const float* __restrict__ w,  const float* __restrict__ bias,
    float* __restrict__ y1)
{
    int gid = blockIdx.x * 256 + threadIdx.x;        // 8*32*4096 = 1,048,576
    int px  = gid & 4095;
    int co  = (gid >> 12) & 31;
    int img = gid >> 17;
    const float* xin = (img < 4) ? (x1 + (size_t)img * NPX)
                                 : (x2 + (size_t)(img - 4) * NPX);
    int r = px >> 6, c = px & 63;
    float acc = bias[co];
#pragma unroll
    for (int dy = 0; dy < 3; ++dy) {
        int rr = r + dy - 1;
        if (rr < 0 || rr > 63) continue;
#pragma unroll
        for (int dx = 0; dx < 3; ++dx) {
            int cc = c + dx - 1;
            if (cc < 0 || cc > 63) continue;
            acc = fmaf(w[co * 9 + dy * 3 + dx], xin[rr * 64 + cc], acc);
        }
    }
    y1[(size_t)img * 32 * NPX + (size_t)co * NPX + px] = acc;
}

// ---------------------------------------------------------------------------
// wtrans: wT[(ci*9+tap)*CO + co] = w[co][ci][tap]. Tiny; runs once per call.
// ---------------------------------------------------------------------------
__global__ __launch_bounds__(256) void wtrans_k(
    const float* __restrict__ w, float* __restrict__ wT,
    int CI9, int CO, int total)
{
    int gid = blockIdx.x * 256 + threadIdx.x;
    if (gid >= total) return;
    int k = gid / CO, co = gid - k * CO;
    wT[gid] = w[(size_t)co * CI9 + k];
}

// ---------------------------------------------------------------------------
// convg: 3x3 SAME conv as register-tile implicit GEMM.
// Block = (row-block of 4 rows, img, 64-co group). 256 threads:
//   co4 = (tid&15)*4  -> thread owns 4 consecutive out channels
//   pxg = tid>>4      -> row_l = pxg>>2 (0..3), c0 = (pxg&3)*16 (16 px)
// acc[4][16] per thread. Per (ci,dy): 9 ds_reads vs 192 FMA.
// LDS: in slab [CIC=16][6 rows][64] = 24 KB, weights [144][64] = 36 KB.
// ---------------------------------------------------------------------------
template <int CI>
__global__ __launch_bounds__(256) void convg_k(
    const float* __restrict__ in,    // [8][CI][64][64]
    const float* __restrict__ wT,    // [CI*9][COT] transposed weights
    const float* __restrict__ bias,  // [COT]
    float* __restrict__ outA,        // dest img 0..3
    float* __restrict__ outB,        // dest img 4..7
    int strideA, int strideB, int COT)
{
    constexpr int CIC = 16;
    __shared__ __align__(16) float in_lds[CIC * 6 * 64];   // 24 KB
    __shared__ __align__(16) float w_lds[CIC * 9 * 64];    // 36 KB

    const int r0  = blockIdx.x * 4;
    const int img = blockIdx.y;
    const int cob = blockIdx.z * 64;
    const int tid = threadIdx.x;
    const int co4 = (tid & 15) * 4;
    const int pxg = tid >> 4;
    const int row_l = pxg >> 2;
    const int c0 = (pxg & 3) * 16;

    const float* ib = in + (size_t)img * CI * NPX;

    float acc[4][16];
#pragma unroll
    for (int e = 0; e < 4; ++e) {
        float bv = bias[cob + co4 + e];
#pragma unroll
        for (int p = 0; p < 16; ++p) acc[e][p] = bv;
    }

    for (int cic = 0; cic < CI; cic += CIC) {
        __syncthreads();
        // stage input slab: 16 ci x 6 rows x 64 cols = 1536 float4
#pragma unroll
        for (int t = 0; t < 6; ++t) {
            int f = tid + t * 256;
            int ci = f / 96, rem = f - ci * 96;
            int dyr = rem >> 4, c4 = rem & 15;
            int gr = r0 + dyr - 1;
            float4 v = make_float4(0.f, 0.f, 0.f, 0.f);
            if (gr >= 0 && gr < 64)
                v = *(const float4*)&ib[(size_t)(cic + ci) * NPX + gr * 64 + c4 * 4];
            *(float4*)&in_lds[(ci * 6 + dyr) * 64 + c4 * 4] = v;
        }
        // stage weights: 144 k-rows x 64 co = 2304 float4
#pragma unroll
        for (int t = 0; t < 9; ++t) {
            int f = tid + t * 256;
            int k = f >> 4, c4 = f & 15;
            *(float4*)&w_lds[k * 64 + c4 * 4] =
                *(const float4*)&wT[(size_t)(cic * 9 + k) * COT + cob + c4 * 4];
        }
        __syncthreads();

        for (int ci = 0; ci < CIC; ++ci) {
#pragma unroll
            for (int dy = 0; dy < 3; ++dy) {
                const float* rp = &in_lds[(ci * 6 + row_l + dy) * 64 + c0];
                float v[18];
                float left  = rp[(c0 == 0)  ? 0 : -1];
                float right = rp[(c0 == 48) ? 0 : 16];
                v[0]  = (c0 == 0)  ? 0.f : left;
                *(float4*)&v[1]  = *(const float4*)&rp[0];
                *(float4*)&v[5]  = *(const float4*)&rp[4];
                *(float4*)&v[9]  = *(const float4*)&rp[8];
                *(float4*)&v[13] = *(const float4*)&rp[12];
                v[17] = (c0 == 48) ? 0.f : right;
                const float* wp = &w_lds[(ci * 9 + dy * 3) * 64 + co4];
                float wv[3][4];
                *(float4*)&wv[0][0] = *(const float4*)&wp[0];
                *(float4*)&wv[1][0] = *(const float4*)&wp[64];
                *(float4*)&wv[2][0] = *(const float4*)&wp[128];
#pragma unroll
                for (int dx = 0; dx < 3; ++dx)
#pragma unroll
                    for (int e = 0; e < 4; ++e)
#pragma unroll
                        for (int p = 0; p < 16; ++p)
                            acc[e][p] = fmaf(wv[dx][e], v[p + dx], acc[e][p]);
            }
        }
    }

    float* dst = (img < 4) ? (outA + (size_t)img * strideA)
                           : (outB + (size_t)(img - 4) * strideB);
    dst += (size_t)(cob + co4) * NPX + (r0 + row_l) * 64 + c0;
#pragma unroll
    for (int e = 0; e < 4; ++e)
#pragma unroll
        for (int q = 0; q < 4; ++q)
            *(float4*)&dst[(size_t)e * NPX + q * 4] = *(float4*)&acc[e][q * 4];
}

// ---------------------------------------------------------------------------
// normB: ||f2_j||^2 per (b, j); also inits minkey to all-ones.
// ---------------------------------------------------------------------------
__global__ __launch_bounds__(256) void normb_k(
    const float* __restrict__ f2, float* __restrict__ normB,
    unsigned long long* __restrict__ minkey)
{
    int gid = blockIdx.x * 256 + threadIdx.x;   // 4*4096
    int b = gid >> 12, j = gid & 4095;
    const float* p = f2 + (size_t)b * 256 * NPX + j;
    float s = 0.f;
#pragma unroll 8
    for (int c = 0; c < 256; ++c) {
        float v = p[(size_t)c * NPX];
        s = fmaf(v, v, s);
    }
    normB[gid] = s;
    minkey[gid] = ~0ull;
}

// ---------------------------------------------------------------------------
// gemm_argmin: per batch, cross = f1^T f2 tile (128i x 128j), fused
// key = ||f2_j||^2 - 2*cross; block-local min then global atomicMin on
// packed (orderable-float << 32 | j) so tie-break = smallest j (JAX argmin).
// Block 256 = 16(ti) x 16(tj); each thread owns an 8x8 register tile.
// ---------------------------------------------------------------------------
__global__ __launch_bounds__(256) void gemm_argmin_k(
    const float* __restrict__ f1base,   // d_out, per-b stride 512*NPX, ch 0..255
    const float* __restrict__ f2base,   // ws,   per-b stride 256*NPX
    const float* __restrict__ normB,    // [4][4096]
    unsigned long long* __restrict__ minkey)  // [4][4096]
{
    __shared__ __align__(16) float smem[8192];  // As[32][128] | Bs[32][128]
    float* As = smem;                   // As[c][i_local]
    float* Bs = smem + 4096;            // Bs[c][j_local]

    const int b  = blockIdx.z;
    const int i0 = blockIdx.y * 128;
    const int j0 = blockIdx.x * 128;
    const float* f1 = f1base + (size_t)b * 512 * NPX;
    const float* f2 = f2base + (size_t)b * 256 * NPX;
    const int tid = threadIdx.x;
    const int ti = tid & 15, tj = tid >> 4;

    float acc[8][8];
#pragma unroll
    for (int i = 0; i < 8; ++i)
#pragma unroll
        for (int j = 0; j < 8; ++j) acc[i][j] = 0.f;

    for (int cb = 0; cb < 256; cb += 32) {
#pragma unroll
        for (int k = 0; k < 4; ++k) {            // A: 32x128 = 1024 float4
            int kk = tid + k * 256;
            int r = kk >> 5, col = kk & 31;
            *(float4*)&As[r * 128 + col * 4] =
                *(const float4*)&f1[(size_t)(cb + r) * NPX + i0 + col * 4];
        }
#pragma unroll
        for (int k = 0; k < 4; ++k) {            // B: 32x128 = 1024 float4
            int kk = tid + k * 256;
            int r = kk >> 5, col = kk & 31;
            *(float4*)&Bs[r * 128 + col * 4] =
                *(const float4*)&f2[(size_t)(cb + r) * NPX + j0 + col * 4];
        }
        __syncthreads();

#pragma unroll 8
        for (int c = 0; c < 32; ++c) {
            float4 a0 = *(float4*)&As[c * 128 + ti * 8];
            float4 a1 = *(float4*)&As[c * 128 + ti * 8 + 4];
            float4 b0 = *(float4*)&Bs[c * 128 + tj * 8];
            float4 b1 = *(float4*)&Bs[c * 128 + tj * 8 + 4];
            float av[8] = {a0.x, a0.y, a0.z, a0.w, a1.x, a1.y, a1.z, a1.w};
            float bv[8] = {b0.x, b0.y, b0.z, b0.w, b1.x, b1.y, b1.z, b1.w};
#pragma unroll
            for (int i = 0; i < 8; ++i)
#pragma unroll
                for (int j = 0; j < 8; ++j)
                    acc[i][j] = fmaf(av[i], bv[j], acc[i][j]);
        }
        __syncthreads();
    }

    // epilogue: dist-key = normB[j] - 2*cross, packed with j; reduce over tj.
    float nb[8];
#pragma unroll
    for (int j = 0; j < 8; ++j) nb[j] = normB[b * 4096 + j0 + tj * 8 + j];

    unsigned long long* red = (unsigned long long*)smem;
#pragma unroll
    for (int ii = 0; ii < 8; ++ii) {
        unsigned long long kb = ~0ull;
#pragma unroll
        for (int j = 0; j < 8; ++j) {
            float d = fmaf(-2.f, acc[ii][j], nb[j]);
            unsigned u = __float_as_uint(d);
            u = (u & 0x80000000u) ? ~u : (u | 0x80000000u);
            unsigned long long key =
                ((unsigned long long)u << 32) | (unsigned)(j0 + tj * 8 + j);
            kb = kb < key ? kb : key;
        }
        red[(ti * 8 + ii) * 17 + tj] = kb;
    }
    __syncthreads();
    if (tid < 128) {
        unsigned long long m = red[tid * 17];
#pragma unroll
        for (int t = 1; t < 16; ++t) {
            unsigned long long v = red[tid * 17 + t];
            m = m < v ? m : v;
        }
        atomicMin(&minkey[(size_t)b * 4096 + i0 + tid], m);
    }
}

// ---------------------------------------------------------------------------
// gather: out[b][256+c][px] = f2[b][c][idx(b,px)]
// ---------------------------------------------------------------------------
__global__ __launch_bounds__(256) void gather_k(
    const unsigned long long* __restrict__ minkey,
    const float* __restrict__ f2, float* __restrict__ out)
{
    int b  = blockIdx.y;
    int px = blockIdx.x * 256 + threadIdx.x;
    int idx = (int)(unsigned)(minkey[(size_t)b * 4096 + px] & 0xffffffffu);
    const float* src = f2 + (size_t)b * 256 * NPX;
    float* dst = out + (size_t)b * 512 * NPX + (size_t)256 * NPX + px;
#pragma unroll 4
    for (int c = 0; c < 256; ++c)
        dst[(size_t)c * NPX] = src[(size_t)c * NPX + idx];
}

// ---------------------------------------------------------------------------
extern "C" void kernel_launch(void* const* d_in, const int* in_sizes, int n_in,
                              void* d_out, int out_size, void* d_ws, size_t ws_size,
                              hipStream_t stream)
{
    const float* x1 = (const float*)d_in[0];
    const float* x2 = (const float*)d_in[1];
    const float* w1 = (const float*)d_in[2];
    const float* b1 = (const float*)d_in[3];
    const float* w2 = (const float*)d_in[4];
    const float* b2 = (const float*)d_in[5];
    const float* w3 = (const float*)d_in[6];
    const float* b3 = (const float*)d_in[7];
    float* out = (float*)d_out;
    char* ws = (char*)d_ws;

    // workspace layout (bytes)
    float* y1 = (float*)(ws);                          //  8*32*4096*4 = 4 MB
    float* y2 = (float*)(ws + 4194304);                //  8*64*4096*4 = 8 MB
    float* f2 = (float*)(ws + 12582912);               //  4*256*4096*4 = 16 MB
    float* normB = (float*)(ws + 29360128);            //  64 KB
    unsigned long long* minkey =
        (unsigned long long*)(ws + 29425664);          // 128 KB
    float* w2T = (float*)(ws + 29556736);              //  72 KB  (288x64)
    float* w3T = (float*)(ws + 29630464);              // 576 KB  (576x256)

    wtrans_k<<<72, 256, 0, stream>>>(w2, w2T, 32 * 9, 64, 64 * 288);
    wtrans_k<<<576, 256, 0, stream>>>(w3, w3T, 64 * 9, 256, 256 * 576);

    conv1_k<<<4096, 256, 0, stream>>>(x1, x2, w1, b1, y1);

    convg_k<32><<<dim3(16, 8, 1), 256, 0, stream>>>(
        y1, w2T, b2, y2, y2 + (size_t)4 * 64 * NPX, 64 * NPX, 64 * NPX, 64);

    // conv3: img 0..3 -> d_out channels 0..255 (that IS f1); img 4..7 -> ws f2
    convg_k<64><<<dim3(16, 8, 4), 256, 0, stream>>>(
        y2, w3T, b3, out, f2, 512 * NPX, 256 * NPX, 256);

    normb_k<<<64, 256, 0, stream>>>(f2, normB, minkey);

    gemm_argmin_k<<<dim3(32, 32, 4), 256, 0, stream>>>(out, f2, normB, minkey);

    gather_k<<<dim3(16, 4), 256, 0, stream>>>(minkey, f2, out);
}

// Round 4
// 466.051 us; speedup vs baseline: 2.4753x; 1.5195x over previous
//
#include <hip/hip_runtime.h>
#include <cstdint>

// Problem constants
// B=4 per input, H=W=64, N=4096 pixels, C3=256 final channels.
// Inputs: x1, x2, w1, b1, w2, b2, w3, b3 (all fp32)
// Output: (4, 512, 64, 64) fp32; ch 0..255 = f1, 256..511 = gathered f2.

#define NPX 4096

using bf16x8 = __attribute__((ext_vector_type(8))) short;
using f32x4  = __attribute__((ext_vector_type(4))) float;

__device__ inline unsigned short f2bf_rne(float x) {
    unsigned u = __float_as_uint(x);
    unsigned r = (u + 0x7fffu + ((u >> 16) & 1u)) >> 16;
    return (unsigned short)r;
}
__device__ inline float bf2f(unsigned short h) {
    return __uint_as_float(((unsigned)h) << 16);
}

#define GLL(gp, lp) __builtin_amdgcn_global_load_lds( \
    (const __attribute__((address_space(1))) void*)(gp), \
    (__attribute__((address_space(3))) void*)(lp), 16, 0, 0)

// ---------------------------------------------------------------------------
// conv1: 1 -> 32 channels, direct. One thread per output element.
// ---------------------------------------------------------------------------
__global__ __launch_bounds__(256) void conv1_k(
    const float* __restrict__ x1, const float* __restrict__ x2,
    const float* __restrict__ w,  const float* __restrict__ bias,
    float* __restrict__ y1)
{
    int gid = blockIdx.x * 256 + threadIdx.x;
    int px  = gid & 4095;
    int co  = (gid >> 12) & 31;
    int img = gid >> 17;
    const float* xin = (img < 4) ? (x1 + (size_t)img * NPX)
                                 : (x2 + (size_t)(img - 4) * NPX);
    int r = px >> 6, c = px & 63;
    float acc = bias[co];
#pragma unroll
    for (int dy = 0; dy < 3; ++dy) {
        int rr = r + dy - 1;
        if (rr < 0 || rr > 63) continue;
#pragma unroll
        for (int dx = 0; dx < 3; ++dx) {
            int cc = c + dx - 1;
            if (cc < 0 || cc > 63) continue;
            acc = fmaf(w[co * 9 + dy * 3 + dx], xin[rr * 64 + cc], acc);
        }
    }
    y1[(size_t)img * 32 * NPX + (size_t)co * NPX + px] = acc;
}

// ---------------------------------------------------------------------------
// wtrans: wT[(ci*9+tap)*CO + co] = w[co][ci][tap].
// ---------------------------------------------------------------------------
__global__ __launch_bounds__(256) void wtrans_k(
    const float* __restrict__ w, float* __restrict__ wT,
    int CI9, int CO, int total)
{
    int gid = blockIdx.x * 256 + threadIdx.x;
    if (gid >= total) return;
    int k = gid / CO, co = gid - k * CO;
    wT[gid] = w[(size_t)co * CI9 + k];
}

// ---------------------------------------------------------------------------
// convg: 3x3 SAME conv, register-tile implicit GEMM (see round 2 notes).
// ---------------------------------------------------------------------------
template <int CI>
__global__ __launch_bounds__(256) void convg_k(
    const float* __restrict__ in,
    const float* __restrict__ wT,
    const float* __restrict__ bias,
    float* __restrict__ outA, float* __restrict__ outB,
    int strideA, int strideB, int COT)
{
    constexpr int CIC = 16;
    __shared__ __align__(16) float in_lds[CIC * 6 * 64];
    __shared__ __align__(16) float w_lds[CIC * 9 * 64];

    const int r0  = blockIdx.x * 4;
    const int img = blockIdx.y;
    const int cob = blockIdx.z * 64;
    const int tid = threadIdx.x;
    const int co4 = (tid & 15) * 4;
    const int pxg = tid >> 4;
    const int row_l = pxg >> 2;
    const int c0 = (pxg & 3) * 16;

    const float* ib = in + (size_t)img * CI * NPX;

    float acc[4][16];
#pragma unroll
    for (int e = 0; e < 4; ++e) {
        float bv = bias[cob + co4 + e];
#pragma unroll
        for (int p = 0; p < 16; ++p) acc[e][p] = bv;
    }

    for (int cic = 0; cic < CI; cic += CIC) {
        __syncthreads();
#pragma unroll
        for (int t = 0; t < 6; ++t) {
            int f = tid + t * 256;
            int ci = f / 96, rem = f - ci * 96;
            int dyr = rem >> 4, c4 = rem & 15;
            int gr = r0 + dyr - 1;
            float4 v = make_float4(0.f, 0.f, 0.f, 0.f);
            if (gr >= 0 && gr < 64)
                v = *(const float4*)&ib[(size_t)(cic + ci) * NPX + gr * 64 + c4 * 4];
            *(float4*)&in_lds[(ci * 6 + dyr) * 64 + c4 * 4] = v;
        }
#pragma unroll
        for (int t = 0; t < 9; ++t) {
            int f = tid + t * 256;
            int k = f >> 4, c4 = f & 15;
            *(float4*)&w_lds[k * 64 + c4 * 4] =
                *(const float4*)&wT[(size_t)(cic * 9 + k) * COT + cob + c4 * 4];
        }
        __syncthreads();

        for (int ci = 0; ci < CIC; ++ci) {
#pragma unroll
            for (int dy = 0; dy < 3; ++dy) {
                const float* rp = &in_lds[(ci * 6 + row_l + dy) * 64 + c0];
                float v[18];
                float left  = rp[(c0 == 0)  ? 0 : -1];
                float right = rp[(c0 == 48) ? 0 : 16];
                v[0]  = (c0 == 0)  ? 0.f : left;
                *(float4*)&v[1]  = *(const float4*)&rp[0];
                *(float4*)&v[5]  = *(const float4*)&rp[4];
                *(float4*)&v[9]  = *(const float4*)&rp[8];
                *(float4*)&v[13] = *(const float4*)&rp[12];
                v[17] = (c0 == 48) ? 0.f : right;
                const float* wp = &w_lds[(ci * 9 + dy * 3) * 64 + co4];
                float wv[3][4];
                *(float4*)&wv[0][0] = *(const float4*)&wp[0];
                *(float4*)&wv[1][0] = *(const float4*)&wp[64];
                *(float4*)&wv[2][0] = *(const float4*)&wp[128];
#pragma unroll
                for (int dx = 0; dx < 3; ++dx)
#pragma unroll
                    for (int e = 0; e < 4; ++e)
#pragma unroll
                        for (int p = 0; p < 16; ++p)
                            acc[e][p] = fmaf(wv[dx][e], v[p + dx], acc[e][p]);
            }
        }
    }

    float* dst = (img < 4) ? (outA + (size_t)img * strideA)
                           : (outB + (size_t)(img - 4) * strideB);
    dst += (size_t)(cob + co4) * NPX + (r0 + row_l) * 64 + c0;
#pragma unroll
    for (int e = 0; e < 4; ++e)
#pragma unroll
        for (int q = 0; q < 4; ++q)
            *(float4*)&dst[(size_t)e * NPX + q * 4] = *(float4*)&acc[e][q * 4];
}

// ---------------------------------------------------------------------------
// splitT: transpose [256 k][4096 m] fp32 -> [4096 m][256 k] bf16 hi + lo.
// 64k x 64m tile per block via padded-LDS transpose.
// ---------------------------------------------------------------------------
__global__ __launch_bounds__(256) void splitT_k(
    const float* __restrict__ src, size_t srcStride,
    unsigned short* __restrict__ dh, unsigned short* __restrict__ dl)
{
    __shared__ float T[64][65];
    const int m0 = blockIdx.x * 64, k0 = blockIdx.y * 64, b = blockIdx.z;
    const float* s = src + (size_t)b * srcStride;
    const int tid = threadIdx.x;
    const int cm = tid & 63, rk = tid >> 6;
#pragma unroll
    for (int t = 0; t < 16; ++t)
        T[rk + t * 4][cm] = s[(size_t)(k0 + rk + t * 4) * NPX + m0 + cm];
    __syncthreads();
    const int ck = tid & 63, rm = tid >> 6;
#pragma unroll
    for (int t = 0; t < 16; ++t) {
        int m = rm + t * 4;
        float v = T[ck][m];
        unsigned short hi = f2bf_rne(v);
        float lo = v - bf2f(hi);
        size_t o = ((size_t)b * NPX + m0 + m) * 256 + k0 + ck;
        dh[o] = hi;
        dl[o] = f2bf_rne(lo);
    }
}

// ---------------------------------------------------------------------------
// normB: ||f2_j||^2 per (b, j); also inits minkey.
// ---------------------------------------------------------------------------
__global__ __launch_bounds__(256) void normb_k(
    const float* __restrict__ f2, float* __restrict__ normB,
    unsigned long long* __restrict__ minkey)
{
    int gid = blockIdx.x * 256 + threadIdx.x;
    int b = gid >> 12, j = gid & 4095;
    const float* p = f2 + (size_t)b * 256 * NPX + j;
    float s = 0.f;
#pragma unroll 8
    for (int c = 0; c < 256; ++c) {
        float v = p[(size_t)c * NPX];
        s = fmaf(v, v, s);
    }
    normB[gid] = s;
    minkey[gid] = ~0ull;
}

// ---------------------------------------------------------------------------
// gemm_argmin_mfma: cross = f1.f2^T via 4x bf16-split MFMA (fp32-equivalent
// accuracy), fused dist-key argmin. Tile 128i x 128j, BK=32, 4 waves 2x2.
// LDS: Ah/Al/Bh/Bl each [128 rows][32 k] bf16, staged with global_load_lds.
// Frag: lane reads row (l&15), k-slice (l>>4)*8 -> b128, uniform banks.
// C/D: col=lane&15 (j), row=(lane>>4)*4+reg (i)  [verified m89].
// ---------------------------------------------------------------------------
__global__ __launch_bounds__(256) void gemm_argmin_mfma_k(
    const unsigned short* __restrict__ f1h, const unsigned short* __restrict__ f1l,
    const unsigned short* __restrict__ f2h, const unsigned short* __restrict__ f2l,
    const float* __restrict__ normB,
    unsigned long long* __restrict__ minkey)
{
    __shared__ unsigned short lds[4][4096];   // Ah | Al | Bh | Bl, 32 KB
    const int b  = blockIdx.z;
    const int i0 = blockIdx.y * 128;
    const int j0 = blockIdx.x * 128;
    const int tid  = threadIdx.x;
    const int lane = tid & 63;
    const int w    = tid >> 6;
    const int wm   = w >> 1, wn = w & 1;

    // staging source pointers: wave w stages rows w*32+q*16+(lane>>2), q=0,1
    const int srow  = w * 32 + (lane >> 2);
    const int skoff = (lane & 3) * 8;
    const unsigned short* pAh = f1h + ((size_t)b * NPX + i0 + srow) * 256 + skoff;
    const unsigned short* pAl = f1l + ((size_t)b * NPX + i0 + srow) * 256 + skoff;
    const unsigned short* pBh = f2h + ((size_t)b * NPX + j0 + srow) * 256 + skoff;
    const unsigned short* pBl = f2l + ((size_t)b * NPX + j0 + srow) * 256 + skoff;
    unsigned short* l0 = &lds[0][0] + w * 1024;   // +lane*16B implicit
    unsigned short* l1 = &lds[1][0] + w * 1024;
    unsigned short* l2 = &lds[2][0] + w * 1024;
    unsigned short* l3 = &lds[3][0] + w * 1024;

    // fragment read offsets (ushort units)
    const int aoff = (wm * 64 + (lane & 15)) * 32 + (lane >> 4) * 8;
    const int boff = (wn * 64 + (lane & 15)) * 32 + (lane >> 4) * 8;

    const f32x4 zero = {0.f, 0.f, 0.f, 0.f};
    f32x4 acc[4][4];
#pragma unroll
    for (int i = 0; i < 4; ++i)
#pragma unroll
        for (int j = 0; j < 4; ++j) acc[i][j] = zero;

    for (int kb = 0; kb < 256; kb += 32) {
        __syncthreads();                       // prev-iter reads done
        GLL(pAh,            l0);
        GLL(pAh + 16 * 256, l0 + 512);
        GLL(pAl,            l1);
        GLL(pAl + 16 * 256, l1 + 512);
        GLL(pBh,            l2);
        GLL(pBh + 16 * 256, l2 + 512);
        GLL(pBl,            l3);
        GLL(pBl + 16 * 256, l3 + 512);
        pAh += 32; pAl += 32; pBh += 32; pBl += 32;
        __syncthreads();                       // vmcnt(0) drained by compiler

        bf16x8 ah[4], al[4], bh[4], bl[4];
#pragma unroll
        for (int mf = 0; mf < 4; ++mf) {
            ah[mf] = *(const bf16x8*)&lds[0][aoff + mf * 512];
            al[mf] = *(const bf16x8*)&lds[1][aoff + mf * 512];
        }
#pragma unroll
        for (int nf = 0; nf < 4; ++nf) {
            bh[nf] = *(const bf16x8*)&lds[2][boff + nf * 512];
            bl[nf] = *(const bf16x8*)&lds[3][boff + nf * 512];
        }
#pragma unroll
        for (int mf = 0; mf < 4; ++mf)
#pragma unroll
            for (int nf = 0; nf < 4; ++nf) {
                f32x4 c = acc[mf][nf];
                c = __builtin_amdgcn_mfma_f32_16x16x32_bf16(ah[mf], bh[nf], c, 0, 0, 0);
                c = __builtin_amdgcn_mfma_f32_16x16x32_bf16(ah[mf], bl[nf], c, 0, 0, 0);
                c = __builtin_amdgcn_mfma_f32_16x16x32_bf16(al[mf], bh[nf], c, 0, 0, 0);
                c = __builtin_amdgcn_mfma_f32_16x16x32_bf16(al[mf], bl[nf], c, 0, 0, 0);
                acc[mf][nf] = c;
            }
    }

    // epilogue: key = normB[j] - 2*cross packed with j; reduce over j-lanes
    float nbv[4];
    const float* nbp = normB + b * 4096 + j0 + wn * 64 + (lane & 15);
#pragma unroll
    for (int nf = 0; nf < 4; ++nf) nbv[nf] = nbp[nf * 16];
    const int jcol = j0 + wn * 64 + (lane & 15);

#pragma unroll
    for (int mf = 0; mf < 4; ++mf) {
#pragma unroll
        for (int reg = 0; reg < 4; ++reg) {
            unsigned long long kmin = ~0ull;
#pragma unroll
            for (int nf = 0; nf < 4; ++nf) {
                float d = fmaf(-2.f, acc[mf][nf][reg], nbv[nf]);
                unsigned u = __float_as_uint(d);
                u = (u & 0x80000000u) ? ~u : (u | 0x80000000u);
                unsigned long long key =
                    ((unsigned long long)u << 32) | (unsigned)(jcol + nf * 16);
                kmin = kmin < key ? kmin : key;
            }
#pragma unroll
            for (int s = 1; s < 16; s <<= 1) {
                unsigned long long o = __shfl_xor(kmin, s, 64);
                kmin = kmin < o ? kmin : o;
            }
            if ((lane & 15) == 0) {
                int i = i0 + wm * 64 + mf * 16 + (lane >> 4) * 4 + reg;
                atomicMin(&minkey[(size_t)b * 4096 + i], kmin);
            }
        }
    }
}

// ---------------------------------------------------------------------------
// fp32 fallback GEMM+argmin (proven round 3) — used if ws too small.
// ---------------------------------------------------------------------------
__global__ __launch_bounds__(256) void gemm_argmin_k(
    const float* __restrict__ f1base, const float* __restrict__ f2base,
    const float* __restrict__ normB, unsigned long long* __restrict__ minkey)
{
    __shared__ __align__(16) float smem[8192];
    float* As = smem;
    float* Bs = smem + 4096;

    const int b  = blockIdx.z;
    const int i0 = blockIdx.y * 128;
    const int j0 = blockIdx.x * 128;
    const float* f1 = f1base + (size_t)b * 512 * NPX;
    const float* f2 = f2base + (size_t)b * 256 * NPX;
    const int tid = threadIdx.x;
    const int ti = tid & 15, tj = tid >> 4;

    float acc[8][8];
#pragma unroll
    for (int i = 0; i < 8; ++i)
#pragma unroll
        for (int j = 0; j < 8; ++j) acc[i][j] = 0.f;

    for (int cb = 0; cb < 256; cb += 32) {
#pragma unroll
        for (int k = 0; k < 4; ++k) {
            int kk = tid + k * 256;
            int r = kk >> 5, col = kk & 31;
            *(float4*)&As[r * 128 + col * 4] =
                *(const float4*)&f1[(size_t)(cb + r) * NPX + i0 + col * 4];
        }
#pragma unroll
        for (int k = 0; k < 4; ++k) {
            int kk = tid + k * 256;
            int r = kk >> 5, col = kk & 31;
            *(float4*)&Bs[r * 128 + col * 4] =
                *(const float4*)&f2[(size_t)(cb + r) * NPX + j0 + col * 4];
        }
        __syncthreads();
#pragma unroll 8
        for (int c = 0; c < 32; ++c) {
            float4 a0 = *(float4*)&As[c * 128 + ti * 8];
            float4 a1 = *(float4*)&As[c * 128 + ti * 8 + 4];
            float4 b0 = *(float4*)&Bs[c * 128 + tj * 8];
            float4 b1 = *(float4*)&Bs[c * 128 + tj * 8 + 4];
            float av[8] = {a0.x, a0.y, a0.z, a0.w, a1.x, a1.y, a1.z, a1.w};
            float bv[8] = {b0.x, b0.y, b0.z, b0.w, b1.x, b1.y, b1.z, b1.w};
#pragma unroll
            for (int i = 0; i < 8; ++i)
#pragma unroll
                for (int j = 0; j < 8; ++j)
                    acc[i][j] = fmaf(av[i], bv[j], acc[i][j]);
        }
        __syncthreads();
    }

    float nb[8];
#pragma unroll
    for (int j = 0; j < 8; ++j) nb[j] = normB[b * 4096 + j0 + tj * 8 + j];

    unsigned long long* red = (unsigned long long*)smem;
#pragma unroll
    for (int ii = 0; ii < 8; ++ii) {
        unsigned long long kb = ~0ull;
#pragma unroll
        for (int j = 0; j < 8; ++j) {
            float d = fmaf(-2.f, acc[ii][j], nb[j]);
            unsigned u = __float_as_uint(d);
            u = (u & 0x80000000u) ? ~u : (u | 0x80000000u);
            unsigned long long key =
                ((unsigned long long)u << 32) | (unsigned)(j0 + tj * 8 + j);
            kb = kb < key ? kb : key;
        }
        red[(ti * 8 + ii) * 17 + tj] = kb;
    }
    __syncthreads();
    if (tid < 128) {
        unsigned long long m = red[tid * 17];
#pragma unroll
        for (int t = 1; t < 16; ++t) {
            unsigned long long v = red[tid * 17 + t];
            m = m < v ? m : v;
        }
        atomicMin(&minkey[(size_t)b * 4096 + i0 + tid], m);
    }
}

// ---------------------------------------------------------------------------
// gather: out[b][256+c][px] = f2[b][c][idx(b,px)]
// ---------------------------------------------------------------------------
__global__ __launch_bounds__(256) void gather_k(
    const unsigned long long* __restrict__ minkey,
    const float* __restrict__ f2, float* __restrict__ out)
{
    int b  = blockIdx.y;
    int px = blockIdx.x * 256 + threadIdx.x;
    int idx = (int)(unsigned)(minkey[(size_t)b * 4096 + px] & 0xffffffffu);
    const float* src = f2 + (size_t)b * 256 * NPX;
    float* dst = out + (size_t)b * 512 * NPX + (size_t)256 * NPX + px;
#pragma unroll 4
    for (int c = 0; c < 256; ++c)
        dst[(size_t)c * NPX] = src[(size_t)c * NPX + idx];
}

// ---------------------------------------------------------------------------
extern "C" void kernel_launch(void* const* d_in, const int* in_sizes, int n_in,
                              void* d_out, int out_size, void* d_ws, size_t ws_size,
                              hipStream_t stream)
{
    const float* x1 = (const float*)d_in[0];
    const float* x2 = (const float*)d_in[1];
    const float* w1 = (const float*)d_in[2];
    const float* b1 = (const float*)d_in[3];
    const float* w2 = (const float*)d_in[4];
    const float* b2 = (const float*)d_in[5];
    const float* w3 = (const float*)d_in[6];
    const float* b3 = (const float*)d_in[7];
    float* out = (float*)d_out;
    char* ws = (char*)d_ws;

    // workspace layout (bytes)
    float* y1 = (float*)(ws);                          //  4 MB
    float* y2 = (float*)(ws + 4194304);                //  8 MB
    float* f2 = (float*)(ws + 12582912);               // 16 MB
    float* normB = (float*)(ws + 29360128);            // 64 KB
    unsigned long long* minkey =
        (unsigned long long*)(ws + 29425664);          // 128 KB
    float* w2T = (float*)(ws + 29556736);              // 72 KB
    float* w3T = (float*)(ws + 29630464);              // 576 KB -> ends 29.5 MB
    // bf16-split arrays (mfma path only)
    unsigned short* f1h = (unsigned short*)(ws + ((size_t)29 << 20) + (1 << 20));   // 30M
    unsigned short* f1l = (unsigned short*)(ws + ((size_t)38 << 20));               // 38M
    unsigned short* f2h = (unsigned short*)(ws + ((size_t)46 << 20));               // 46M
    unsigned short* f2l = (unsigned short*)(ws + ((size_t)54 << 20));               // 54M..62M

    wtrans_k<<<72, 256, 0, stream>>>(w2, w2T, 32 * 9, 64, 64 * 288);
    wtrans_k<<<576, 256, 0, stream>>>(w3, w3T, 64 * 9, 256, 256 * 576);

    conv1_k<<<4096, 256, 0, stream>>>(x1, x2, w1, b1, y1);

    convg_k<32><<<dim3(16, 8, 1), 256, 0, stream>>>(
        y1, w2T, b2, y2, y2 + (size_t)4 * 64 * NPX, 64 * NPX, 64 * NPX, 64);

    convg_k<64><<<dim3(16, 8, 4), 256, 0, stream>>>(
        y2, w3T, b3, out, f2, 512 * NPX, 256 * NPX, 256);

    normb_k<<<64, 256, 0, stream>>>(f2, normB, minkey);

    if (ws_size >= ((size_t)62 << 20)) {
        splitT_k<<<dim3(64, 4, 4), 256, 0, stream>>>(out, (size_t)512 * NPX, f1h, f1l);
        splitT_k<<<dim3(64, 4, 4), 256, 0, stream>>>(f2,  (size_t)256 * NPX, f2h, f2l);
        gemm_argmin_mfma_k<<<dim3(32, 32, 4), 256, 0, stream>>>(
            f1h, f1l, f2h, f2l, normB, minkey);
    } else {
        gemm_argmin_k<<<dim3(32, 32, 4), 256, 0, stream>>>(out, f2, normB, minkey);
    }

    gather_k<<<dim3(16, 4), 256, 0, stream>>>(minkey, f2, out);
}

// Round 5
// 373.662 us; speedup vs baseline: 3.0873x; 1.2473x over previous
//
#include <hip/hip_runtime.h>
#include <cstdint>

// B=4 per input, H=W=64, N=4096 px, C3=256. Output (4,512,64,64) fp32.
#define NPX 4096

using bf16x8 = __attribute__((ext_vector_type(8))) short;
using f32x4  = __attribute__((ext_vector_type(4))) float;

__device__ inline unsigned short f2bf_rne(float x) {
    unsigned u = __float_as_uint(x);
    unsigned r = (u + 0x7fffu + ((u >> 16) & 1u)) >> 16;
    return (unsigned short)r;
}
__device__ inline float bf2f(unsigned short h) {
    return __uint_as_float(((unsigned)h) << 16);
}

#define GLL(gp, lp) __builtin_amdgcn_global_load_lds( \
    (const __attribute__((address_space(1))) void*)(gp), \
    (__attribute__((address_space(3))) void*)(lp), 16, 0, 0)

// ---------------------------------------------------------------------------
// conv1: 1 -> 32 channels, direct.
// ---------------------------------------------------------------------------
__global__ __launch_bounds__(256) void conv1_k(
    const float* __restrict__ x1, const float* __restrict__ x2,
    const float* __restrict__ w,  const float* __restrict__ bias,
    float* __restrict__ y1)
{
    int gid = blockIdx.x * 256 + threadIdx.x;
    int px  = gid & 4095;
    int co  = (gid >> 12) & 31;
    int img = gid >> 17;
    const float* xin = (img < 4) ? (x1 + (size_t)img * NPX)
                                 : (x2 + (size_t)(img - 4) * NPX);
    int r = px >> 6, c = px & 63;
    float acc = bias[co];
#pragma unroll
    for (int dy = 0; dy < 3; ++dy) {
        int rr = r + dy - 1;
        if (rr < 0 || rr > 63) continue;
#pragma unroll
        for (int dx = 0; dx < 3; ++dx) {
            int cc = c + dx - 1;
            if (cc < 0 || cc > 63) continue;
            acc = fmaf(w[co * 9 + dy * 3 + dx], xin[rr * 64 + cc], acc);
        }
    }
    y1[(size_t)img * 32 * NPX + (size_t)co * NPX + px] = acc;
}

// ---------------------------------------------------------------------------
// wtrans: wT[(ci*9+tap)*CO + co] = w[co][ci][tap]  (conv2 only)
// ---------------------------------------------------------------------------
__global__ __launch_bounds__(256) void wtrans_k(
    const float* __restrict__ w, float* __restrict__ wT,
    int CI9, int CO, int total)
{
    int gid = blockIdx.x * 256 + threadIdx.x;
    if (gid >= total) return;
    int k = gid / CO, co = gid - k * CO;
    wT[gid] = w[(size_t)co * CI9 + k];
}

// ---------------------------------------------------------------------------
// convg: conv2 (32->64), register-tile implicit GEMM (proven round 3).
// ---------------------------------------------------------------------------
template <int CI>
__global__ __launch_bounds__(256) void convg_k(
    const float* __restrict__ in,
    const float* __restrict__ wT,
    const float* __restrict__ bias,
    float* __restrict__ outA, float* __restrict__ outB,
    int strideA, int strideB, int COT)
{
    constexpr int CIC = 16;
    __shared__ __align__(16) float in_lds[CIC * 6 * 64];
    __shared__ __align__(16) float w_lds[CIC * 9 * 64];

    const int r0  = blockIdx.x * 4;
    const int img = blockIdx.y;
    const int cob = blockIdx.z * 64;
    const int tid = threadIdx.x;
    const int co4 = (tid & 15) * 4;
    const int pxg = tid >> 4;
    const int row_l = pxg >> 2;
    const int c0 = (pxg & 3) * 16;

    const float* ib = in + (size_t)img * CI * NPX;

    float acc[4][16];
#pragma unroll
    for (int e = 0; e < 4; ++e) {
        float bv = bias[cob + co4 + e];
#pragma unroll
        for (int p = 0; p < 16; ++p) acc[e][p] = bv;
    }

    for (int cic = 0; cic < CI; cic += CIC) {
        __syncthreads();
#pragma unroll
        for (int t = 0; t < 6; ++t) {
            int f = tid + t * 256;
            int ci = f / 96, rem = f - ci * 96;
            int dyr = rem >> 4, c4 = rem & 15;
            int gr = r0 + dyr - 1;
            float4 v = make_float4(0.f, 0.f, 0.f, 0.f);
            if (gr >= 0 && gr < 64)
                v = *(const float4*)&ib[(size_t)(cic + ci) * NPX + gr * 64 + c4 * 4];
            *(float4*)&in_lds[(ci * 6 + dyr) * 64 + c4 * 4] = v;
        }
#pragma unroll
        for (int t = 0; t < 9; ++t) {
            int f = tid + t * 256;
            int k = f >> 4, c4 = f & 15;
            *(float4*)&w_lds[k * 64 + c4 * 4] =
                *(const float4*)&wT[(size_t)(cic * 9 + k) * COT + cob + c4 * 4];
        }
        __syncthreads();

        for (int ci = 0; ci < CIC; ++ci) {
#pragma unroll
            for (int dy = 0; dy < 3; ++dy) {
                const float* rp = &in_lds[(ci * 6 + row_l + dy) * 64 + c0];
                float v[18];
                float left  = rp[(c0 == 0)  ? 0 : -1];
                float right = rp[(c0 == 48) ? 0 : 16];
                v[0]  = (c0 == 0)  ? 0.f : left;
                *(float4*)&v[1]  = *(const float4*)&rp[0];
                *(float4*)&v[5]  = *(const float4*)&rp[4];
                *(float4*)&v[9]  = *(const float4*)&rp[8];
                *(float4*)&v[13] = *(const float4*)&rp[12];
                v[17] = (c0 == 48) ? 0.f : right;
                const float* wp = &w_lds[(ci * 9 + dy * 3) * 64 + co4];
                float wv[3][4];
                *(float4*)&wv[0][0] = *(const float4*)&wp[0];
                *(float4*)&wv[1][0] = *(const float4*)&wp[64];
                *(float4*)&wv[2][0] = *(const float4*)&wp[128];
#pragma unroll
                for (int dx = 0; dx < 3; ++dx)
#pragma unroll
                    for (int e = 0; e < 4; ++e)
#pragma unroll
                        for (int p = 0; p < 16; ++p)
                            acc[e][p] = fmaf(wv[dx][e], v[p + dx], acc[e][p]);
            }
        }
    }

    float* dst = (img < 4) ? (outA + (size_t)img * strideA)
                           : (outB + (size_t)(img - 4) * strideB);
    dst += (size_t)(cob + co4) * NPX + (r0 + row_l) * 64 + c0;
#pragma unroll
    for (int e = 0; e < 4; ++e)
#pragma unroll
        for (int q = 0; q < 4; ++q)
            *(float4*)&dst[(size_t)e * NPX + q * 4] = *(float4*)&acc[e][q * 4];
}

// ---------------------------------------------------------------------------
// wprep: w3 [256co][64ci][9tap] -> frag-contiguous bf16 h/l buffer:
// [cogrp2][wm2][tap9][chunk2][split2][mf4][lane64][e8] ushort (576 KB).
// co = cg*128+wm*64+mf*16+(lane&15); ci = chunk*32+(lane>>4)*8+e.
// ---------------------------------------------------------------------------
__global__ __launch_bounds__(256) void wprep_k(
    const float* __restrict__ w3, unsigned short* __restrict__ w3f)
{
    int i = blockIdx.x * 256 + threadIdx.x;      // 147456 threads
    if (i >= 147456) return;
    int tap = i % 9;  int t2 = i / 9;
    int ci = t2 & 63; int co = t2 >> 6;
    float v = w3[(size_t)(co * 64 + ci) * 9 + tap];
    unsigned short hi = f2bf_rne(v);
    unsigned short lo = f2bf_rne(v - bf2f(hi));
    int cg = co >> 7, wm = (co >> 6) & 1, mf = (co >> 4) & 3, l15 = co & 15;
    int ch = ci >> 5, q = (ci >> 3) & 3, e = ci & 7;
    int lane = q * 16 + l15;
    size_t o = (size_t)(cg * 2 + wm) * 73728 + tap * 8192 + ch * 4096
             + mf * 512 + lane * 8 + e;
    w3f[o] = hi;
    w3f[o + 2048] = lo;
}

// ---------------------------------------------------------------------------
// y2prep: y2 [8][64ci][4096px] fp32 -> y2pre h/l [8][66 rows][64px][64ci]
// bf16 (plain layout, zero guard rows 0 and 65). LDS transpose per (img,row).
// ---------------------------------------------------------------------------
__global__ __launch_bounds__(256) void y2prep_k(
    const float* __restrict__ y2,
    unsigned short* __restrict__ h, unsigned short* __restrict__ l)
{
    const int rg = blockIdx.x;   // 0..65
    const int img = blockIdx.y;
    const int tid = threadIdx.x;
    const size_t base = ((size_t)img * 66 + rg) * 4096;
    if (rg == 0 || rg == 65) {
#pragma unroll
        for (int t = 0; t < 16; ++t) {
            h[base + tid + t * 256] = 0;
            l[base + tid + t * 256] = 0;
        }
        return;
    }
    __shared__ float T[64][65];
    const int row = rg - 1;
#pragma unroll
    for (int t = 0; t < 16; ++t) {
        int ii = tid + t * 256;
        int ci = ii >> 6, col = ii & 63;
        T[ci][col] = y2[(size_t)img * 262144 + (size_t)ci * NPX + row * 64 + col];
    }
    __syncthreads();
#pragma unroll
    for (int t = 0; t < 16; ++t) {
        int ii = tid + t * 256;
        int ci = ii & 63, px = ii >> 6;
        float v = T[ci][px];
        unsigned short hi = f2bf_rne(v);
        h[base + px * 64 + ci] = hi;
        l[base + px * 64 + ci] = f2bf_rne(v - bf2f(hi));
    }
}

// ---------------------------------------------------------------------------
// conv3m: conv3 (64->256) as 9-tap shifted MFMA GEMM, bf16-split-3.
// Grid (16 pxgrp, 8 img, 2 cogrp), 512 thr = 8 waves (wm2 x wn4).
// X: 6 rows [384px][64ci] h/l in LDS (96 KB), staged once by GLL with
// pre-swizzled source (kb ^= px&7) -> conflict-free shifted ds_read_b128.
// W: frag-contiguous global (L2-hot), double-buffered registers, no barrier.
// ---------------------------------------------------------------------------
__global__ __launch_bounds__(512, 2) void conv3m_k(
    const unsigned short* __restrict__ y2ph,
    const unsigned short* __restrict__ y2pl,
    const unsigned short* __restrict__ w3f,
    const float* __restrict__ b3,
    float* __restrict__ out, float* __restrict__ f2)
{
    __shared__ unsigned short xlds[49152];   // [2 split][384 px][64 ci]
    const int pxg = blockIdx.x;
    const int img = blockIdx.y;
    const int cg  = blockIdx.z;
    const int tid = threadIdx.x;
    const int lane = tid & 63;
    const int wid = tid >> 6;
    const int wm = wid >> 2, wn = wid & 3;
    const int q16 = lane >> 4, l15 = lane & 15;
    const int r0 = pxg * 4;
    const int px0 = pxg * 256;
    const int cob = cg * 128;

    // stage X (12 GLL / thread); dest linear, source kb-swizzled
    const unsigned short* yh = y2ph + (size_t)img * 270336;
    const unsigned short* yl = y2pl + (size_t)img * 270336;
#pragma unroll
    for (int it = 0; it < 12; ++it) {
        int dbase = it * 8192 + wid * 1024;
        int d = dbase + lane * 16;
        int s = d >= 49152;
        int r = d - (s ? 49152 : 0);
        int pxl = r >> 7;
        int kbs = (r >> 4) & 7;
        int kb  = kbs ^ (pxl & 7);
        int rg  = r0 + (pxl >> 6);
        int col = pxl & 63;
        const unsigned short* src = (s ? yl : yh) + ((rg << 6) + col) * 64 + kb * 8;
        GLL(src, (char*)xlds + dbase);
    }

    // W double-buffer, stage 0
    const unsigned short* wbase = w3f + (size_t)(cg * 2 + wm) * 73728 + lane * 8;
    bf16x8 awh[2][4], awl[2][4];
#pragma unroll
    for (int mf = 0; mf < 4; ++mf) {
        awh[0][mf] = *(const bf16x8*)(wbase + mf * 512);
        awl[0][mf] = *(const bf16x8*)(wbase + 2048 + mf * 512);
    }

    // acc init with bias
    f32x4 acc[4][4];
#pragma unroll
    for (int mf = 0; mf < 4; ++mf) {
        float bv[4];
#pragma unroll
        for (int r = 0; r < 4; ++r)
            bv[r] = b3[cob + wm * 64 + mf * 16 + q16 * 4 + r];
#pragma unroll
        for (int nf = 0; nf < 4; ++nf)
#pragma unroll
            for (int r = 0; r < 4; ++r) acc[mf][nf][r] = bv[r];
    }

    const int plb = wn * 64 + 64 + l15;          // local px row, nf=0
    const int key_m = (lane + 7) & 7;            // dx=-1
    const int key_0 = lane & 7;                  // dx= 0
    const int key_p = (lane + 1) & 7;            // dx=+1
    const bf16x8 z8 = {0, 0, 0, 0, 0, 0, 0, 0};

    __syncthreads();

#pragma unroll
    for (int ch = 0; ch < 2; ++ch) {
#pragma unroll
        for (int tap = 0; tap < 9; ++tap) {
            const int st = ch * 9 + tap;
            const int cur = st & 1;
            if (st < 17) {                        // prefetch next W stage
                const int nst = st + 1;
                const int nch = nst / 9, ntap = nst % 9;
#pragma unroll
                for (int mf = 0; mf < 4; ++mf) {
                    awh[cur ^ 1][mf] = *(const bf16x8*)(wbase + ntap * 8192 + nch * 4096 + mf * 512);
                    awl[cur ^ 1][mf] = *(const bf16x8*)(wbase + ntap * 8192 + nch * 4096 + 2048 + mf * 512);
                }
            }
            const int dy = tap / 3 - 1, dx = tap % 3 - 1;
            const int key = (dx < 0) ? key_m : ((dx > 0) ? key_p : key_0);
            bf16x8 bh[4], bl[4];
#pragma unroll
            for (int nf = 0; nf < 4; ++nf) {
                int row = plb + nf * 16 + dy * 64 + dx;
                row = row < 0 ? 0 : (row > 383 ? 383 : row);
                int kbs = (q16 + ch * 4) ^ key;
                int ba = row * 128 + kbs * 16;
                bh[nf] = *(const bf16x8*)((const char*)xlds + ba);
                bl[nf] = *(const bf16x8*)((const char*)xlds + ba + 49152);
                if (dx < 0 && nf == 0) {
                    bh[nf] = (l15 == 0) ? z8 : bh[nf];
                    bl[nf] = (l15 == 0) ? z8 : bl[nf];
                }
                if (dx > 0 && nf == 3) {
                    bh[nf] = (l15 == 15) ? z8 : bh[nf];
                    bl[nf] = (l15 == 15) ? z8 : bl[nf];
                }
            }
#pragma unroll
            for (int mf = 0; mf < 4; ++mf)
#pragma unroll
                for (int nf = 0; nf < 4; ++nf) {
                    f32x4 c = acc[mf][nf];
                    c = __builtin_amdgcn_mfma_f32_16x16x32_bf16(awh[cur][mf], bh[nf], c, 0, 0, 0);
                    c = __builtin_amdgcn_mfma_f32_16x16x32_bf16(awh[cur][mf], bl[nf], c, 0, 0, 0);
                    c = __builtin_amdgcn_mfma_f32_16x16x32_bf16(awl[cur][mf], bh[nf], c, 0, 0, 0);
                    acc[mf][nf] = c;
                }
        }
    }

    float* dst = (img < 4) ? out + (size_t)img * 512 * NPX
                           : f2  + (size_t)(img - 4) * 256 * NPX;
#pragma unroll
    for (int mf = 0; mf < 4; ++mf)
#pragma unroll
        for (int nf = 0; nf < 4; ++nf)
#pragma unroll
            for (int r = 0; r < 4; ++r) {
                int co = cob + wm * 64 + mf * 16 + q16 * 4 + r;
                int px = px0 + wn * 64 + nf * 16 + l15;
                dst[(size_t)co * NPX + px] = acc[mf][nf][r];
            }
}

// ---------------------------------------------------------------------------
// splitT: [256k][4096m] fp32 -> [4096m][256k] bf16 hi+lo (LDS transpose).
// ---------------------------------------------------------------------------
__global__ __launch_bounds__(256) void splitT_k(
    const float* __restrict__ src, size_t srcStride,
    unsigned short* __restrict__ dh, unsigned short* __restrict__ dl)
{
    __shared__ float T[64][65];
    const int m0 = blockIdx.x * 64, k0 = blockIdx.y * 64, b = blockIdx.z;
    const float* s = src + (size_t)b * srcStride;
    const int tid = threadIdx.x;
    const int cm = tid & 63, rk = tid >> 6;
#pragma unroll
    for (int t = 0; t < 16; ++t)
        T[rk + t * 4][cm] = s[(size_t)(k0 + rk + t * 4) * NPX + m0 + cm];
    __syncthreads();
    const int ck = tid & 63, rm = tid >> 6;
#pragma unroll
    for (int t = 0; t < 16; ++t) {
        int m = rm + t * 4;
        float v = T[ck][m];
        unsigned short hi = f2bf_rne(v);
        float lo = v - bf2f(hi);
        size_t o = ((size_t)b * NPX + m0 + m) * 256 + k0 + ck;
        dh[o] = hi;
        dl[o] = f2bf_rne(lo);
    }
}

// ---------------------------------------------------------------------------
// normB + minkey init
// ---------------------------------------------------------------------------
__global__ __launch_bounds__(256) void normb_k(
    const float* __restrict__ f2, float* __restrict__ normB,
    unsigned long long* __restrict__ minkey)
{
    int gid = blockIdx.x * 256 + threadIdx.x;
    int b = gid >> 12, j = gid & 4095;
    const float* p = f2 + (size_t)b * 256 * NPX + j;
    float s = 0.f;
#pragma unroll 8
    for (int c = 0; c < 256; ++c) {
        float v = p[(size_t)c * NPX];
        s = fmaf(v, v, s);
    }
    normB[gid] = s;
    minkey[gid] = ~0ull;
}

// ---------------------------------------------------------------------------
// gemm_argmin_mfma (proven round 4): 4x bf16-split MFMA + fused argmin.
// ---------------------------------------------------------------------------
__global__ __launch_bounds__(256) void gemm_argmin_mfma_k(
    const unsigned short* __restrict__ f1h, const unsigned short* __restrict__ f1l,
    const unsigned short* __restrict__ f2h, const unsigned short* __restrict__ f2l,
    const float* __restrict__ normB,
    unsigned long long* __restrict__ minkey)
{
    __shared__ unsigned short lds[4][4096];
    const int b  = blockIdx.z;
    const int i0 = blockIdx.y * 128;
    const int j0 = blockIdx.x * 128;
    const int tid  = threadIdx.x;
    const int lane = tid & 63;
    const int w    = tid >> 6;
    const int wm   = w >> 1, wn = w & 1;

    const int srow  = w * 32 + (lane >> 2);
    const int skoff = (lane & 3) * 8;
    const unsigned short* pAh = f1h + ((size_t)b * NPX + i0 + srow) * 256 + skoff;
    const unsigned short* pAl = f1l + ((size_t)b * NPX + i0 + srow) * 256 + skoff;
    const unsigned short* pBh = f2h + ((size_t)b * NPX + j0 + srow) * 256 + skoff;
    const unsigned short* pBl = f2l + ((size_t)b * NPX + j0 + srow) * 256 + skoff;
    unsigned short* l0 = &lds[0][0] + w * 1024;
    unsigned short* l1 = &lds[1][0] + w * 1024;
    unsigned short* l2 = &lds[2][0] + w * 1024;
    unsigned short* l3 = &lds[3][0] + w * 1024;

    const int aoff = (wm * 64 + (lane & 15)) * 32 + (lane >> 4) * 8;
    const int boff = (wn * 64 + (lane & 15)) * 32 + (lane >> 4) * 8;

    const f32x4 zero = {0.f, 0.f, 0.f, 0.f};
    f32x4 acc[4][4];
#pragma unroll
    for (int i = 0; i < 4; ++i)
#pragma unroll
        for (int j = 0; j < 4; ++j) acc[i][j] = zero;

    for (int kb = 0; kb < 256; kb += 32) {
        __syncthreads();
        GLL(pAh,            l0);
        GLL(pAh + 16 * 256, l0 + 512);
        GLL(pAl,            l1);
        GLL(pAl + 16 * 256, l1 + 512);
        GLL(pBh,            l2);
        GLL(pBh + 16 * 256, l2 + 512);
        GLL(pBl,            l3);
        GLL(pBl + 16 * 256, l3 + 512);
        pAh += 32; pAl += 32; pBh += 32; pBl += 32;
        __syncthreads();

        bf16x8 ah[4], al[4], bh[4], bl[4];
#pragma unroll
        for (int mf = 0; mf < 4; ++mf) {
            ah[mf] = *(const bf16x8*)&lds[0][aoff + mf * 512];
            al[mf] = *(const bf16x8*)&lds[1][aoff + mf * 512];
        }
#pragma unroll
        for (int nf = 0; nf < 4; ++nf) {
            bh[nf] = *(const bf16x8*)&lds[2][boff + nf * 512];
            bl[nf] = *(const bf16x8*)&lds[3][boff + nf * 512];
        }
#pragma unroll
        for (int mf = 0; mf < 4; ++mf)
#pragma unroll
            for (int nf = 0; nf < 4; ++nf) {
                f32x4 c = acc[mf][nf];
                c = __builtin_amdgcn_mfma_f32_16x16x32_bf16(ah[mf], bh[nf], c, 0, 0, 0);
                c = __builtin_amdgcn_mfma_f32_16x16x32_bf16(ah[mf], bl[nf], c, 0, 0, 0);
                c = __builtin_amdgcn_mfma_f32_16x16x32_bf16(al[mf], bh[nf], c, 0, 0, 0);
                c = __builtin_amdgcn_mfma_f32_16x16x32_bf16(al[mf], bl[nf], c, 0, 0, 0);
                acc[mf][nf] = c;
            }
    }

    float nbv[4];
    const float* nbp = normB + b * 4096 + j0 + wn * 64 + (lane & 15);
#pragma unroll
    for (int nf = 0; nf < 4; ++nf) nbv[nf] = nbp[nf * 16];
    const int jcol = j0 + wn * 64 + (lane & 15);

#pragma unroll
    for (int mf = 0; mf < 4; ++mf) {
#pragma unroll
        for (int reg = 0; reg < 4; ++reg) {
            unsigned long long kmin = ~0ull;
#pragma unroll
            for (int nf = 0; nf < 4; ++nf) {
                float d = fmaf(-2.f, acc[mf][nf][reg], nbv[nf]);
                unsigned u = __float_as_uint(d);
                u = (u & 0x80000000u) ? ~u : (u | 0x80000000u);
                unsigned long long key =
                    ((unsigned long long)u << 32) | (unsigned)(jcol + nf * 16);
                kmin = kmin < key ? kmin : key;
            }
#pragma unroll
            for (int s = 1; s < 16; s <<= 1) {
                unsigned long long o = __shfl_xor(kmin, s, 64);
                kmin = kmin < o ? kmin : o;
            }
            if ((lane & 15) == 0) {
                int i = i0 + wm * 64 + mf * 16 + (lane >> 4) * 4 + reg;
                atomicMin(&minkey[(size_t)b * 4096 + i], kmin);
            }
        }
    }
}

// ---------------------------------------------------------------------------
// gather
// ---------------------------------------------------------------------------
__global__ __launch_bounds__(256) void gather_k(
    const unsigned long long* __restrict__ minkey,
    const float* __restrict__ f2, float* __restrict__ out)
{
    int b  = blockIdx.y;
    int px = blockIdx.x * 256 + threadIdx.x;
    int idx = (int)(unsigned)(minkey[(size_t)b * 4096 + px] & 0xffffffffu);
    const float* src = f2 + (size_t)b * 256 * NPX;
    float* dst = out + (size_t)b * 512 * NPX + (size_t)256 * NPX + px;
#pragma unroll 4
    for (int c = 0; c < 256; ++c)
        dst[(size_t)c * NPX] = src[(size_t)c * NPX + idx];
}

// ---------------------------------------------------------------------------
extern "C" void kernel_launch(void* const* d_in, const int* in_sizes, int n_in,
                              void* d_out, int out_size, void* d_ws, size_t ws_size,
                              hipStream_t stream)
{
    const float* x1 = (const float*)d_in[0];
    const float* x2 = (const float*)d_in[1];
    const float* w1 = (const float*)d_in[2];
    const float* b1 = (const float*)d_in[3];
    const float* w2 = (const float*)d_in[4];
    const float* b2 = (const float*)d_in[5];
    const float* w3 = (const float*)d_in[6];
    const float* b3 = (const float*)d_in[7];
    float* out = (float*)d_out;
    char* ws = (char*)d_ws;

    // ws layout (bytes); total high-water 55.7 MB (<62 MB proven available)
    float* y1 = (float*)(ws);                               // 0..4M    (dead after conv2)
    float* y2 = (float*)(ws + 4194304);                     // 4..12M   (dead after y2prep)
    float* f2 = (float*)(ws + 12582912);                    // 12..28M  (live to end)
    float* normB = (float*)(ws + 29360128);
    unsigned long long* minkey = (unsigned long long*)(ws + 29425664);
    float* w2T = (float*)(ws + 29556736);
    unsigned short* w3f  = (unsigned short*)(ws + 29630464);   // 576 KB
    unsigned short* y2ph = (unsigned short*)(ws + 30220288);   // 4.2 MB (dead after conv3)
    unsigned short* y2pl = (unsigned short*)(ws + 34545664);   // 4.2 MB (dead after conv3)
    unsigned short* f1h  = (unsigned short*)(ws);              // overlays y1+y2
    unsigned short* f1l  = (unsigned short*)(ws + 30220288);   // overlays y2pre
    unsigned short* f2h  = (unsigned short*)(ws + 38871040);
    unsigned short* f2l  = (unsigned short*)(ws + 47259648);   // ends 55.65M

    wtrans_k<<<72, 256, 0, stream>>>(w2, w2T, 32 * 9, 64, 64 * 288);
    wprep_k<<<576, 256, 0, stream>>>(w3, w3f);

    conv1_k<<<4096, 256, 0, stream>>>(x1, x2, w1, b1, y1);

    convg_k<32><<<dim3(16, 8, 1), 256, 0, stream>>>(
        y1, w2T, b2, y2, y2 + (size_t)4 * 64 * NPX, 64 * NPX, 64 * NPX, 64);

    y2prep_k<<<dim3(66, 8), 256, 0, stream>>>(y2, y2ph, y2pl);

    conv3m_k<<<dim3(16, 8, 2), 512, 0, stream>>>(y2ph, y2pl, w3f, b3, out, f2);

    normb_k<<<64, 256, 0, stream>>>(f2, normB, minkey);

    splitT_k<<<dim3(64, 4, 4), 256, 0, stream>>>(out, (size_t)512 * NPX, f1h, f1l);
    splitT_k<<<dim3(64, 4, 4), 256, 0, stream>>>(f2,  (size_t)256 * NPX, f2h, f2l);

    gemm_argmin_mfma_k<<<dim3(32, 32, 4), 256, 0, stream>>>(
        f1h, f1l, f2h, f2l, normB, minkey);

    gather_k<<<dim3(16, 4), 256, 0, stream>>>(minkey, f2, out);
}